// Round 5
// baseline (386.030 us; speedup 1.0000x reference)
//
#include <hip/hip_runtime.h>
#include <stdint.h>

// Problem shape (fixed by reference): x[4,2048,4096] f32, CB[4096,4096] i8, SCB[4096] f32
static constexpr int Mtot = 8192;   // B*S
static constexpr int Ntot = 4096;   // OUT
static constexpr int Ktot = 4096;   // IN

using i32x4 = __attribute__((ext_vector_type(4))) int;
using i32x16 = __attribute__((ext_vector_type(16))) int;

#define GLD16(gptr, lptr)                                                                   \
  __builtin_amdgcn_global_load_lds((const __attribute__((address_space(1))) void*)(gptr),   \
                                   (__attribute__((address_space(3))) void*)(lptr), 16, 0, 0)
#define WAITVM(N) asm volatile("s_waitcnt vmcnt(" #N ")" ::: "memory")
#define MFMA32(a, b, c) __builtin_amdgcn_mfma_i32_32x32x32_i8((a), (b), (c), 0, 0, 0)

// ---------------------------------------------------------------------------
// Kernel 1 (fused prep):
//  blocks [0, 16384)      : repack CB int32 -> int8
//  blocks [16384, 24576)  : row-wise dynamic int8 quant of x (one block/row)
// ---------------------------------------------------------------------------
__global__ __launch_bounds__(256) void prep_kernel(const int* __restrict__ cb32,
                                                   int8_t* __restrict__ cb8,
                                                   const float* __restrict__ x,
                                                   int8_t* __restrict__ xq,
                                                   float* __restrict__ sx) {
  __shared__ float wmax[4];
  if (blockIdx.x < 16384) {
    const int idx = blockIdx.x * 256 + threadIdx.x;  // one int4 -> one packed int
    const int4 v = reinterpret_cast<const int4*>(cb32)[idx];
    const unsigned packed = (unsigned)(v.x & 0xff) | ((unsigned)(v.y & 0xff) << 8) |
                            ((unsigned)(v.z & 0xff) << 16) | ((unsigned)(v.w & 0xff) << 24);
    reinterpret_cast<unsigned*>(cb8)[idx] = packed;
    return;
  }
  const int row = blockIdx.x - 16384;
  const float4* xr = reinterpret_cast<const float4*>(x + (size_t)row * Ktot);
  float4 v[4];
  float am = 0.f;
#pragma unroll
  for (int i = 0; i < 4; ++i) {
    v[i] = xr[threadIdx.x + i * 256];
    am = fmaxf(am, fmaxf(fmaxf(fabsf(v[i].x), fabsf(v[i].y)),
                         fmaxf(fabsf(v[i].z), fabsf(v[i].w))));
  }
#pragma unroll
  for (int off = 32; off > 0; off >>= 1) am = fmaxf(am, __shfl_xor(am, off));
  if ((threadIdx.x & 63) == 0) wmax[threadIdx.x >> 6] = am;
  __syncthreads();
  am = fmaxf(fmaxf(wmax[0], wmax[1]), fmaxf(wmax[2], wmax[3]));
  const float inv = 127.0f / am;
  if (threadIdx.x == 0) sx[row] = am * (1.0f / 127.0f);
  unsigned* dq = reinterpret_cast<unsigned*>(xq + (size_t)row * Ktot);
#pragma unroll
  for (int i = 0; i < 4; ++i) {
    const int q0 = (int)rintf(v[i].x * inv);
    const int q1 = (int)rintf(v[i].y * inv);
    const int q2 = (int)rintf(v[i].z * inv);
    const int q3 = (int)rintf(v[i].w * inv);
    dq[threadIdx.x + i * 256] = (unsigned)(q0 & 0xff) | ((unsigned)(q1 & 0xff) << 8) |
                                ((unsigned)(q2 & 0xff) << 16) | ((unsigned)(q3 & 0xff) << 24);
  }
}

// ---------------------------------------------------------------------------
// Kernel 2: int8 GEMM, 256x256 tile. r5: mfma_i32_32x32x32_i8 (4404 TOPS
// ceiling vs 3944 for 16x16x64; HALF the MFMA instruction count -> frees SIMD
// issue slots for the co-wave's ds_reads) on the r4 sync skeleton:
//   BK=128 bytes, 512 threads = 8 waves (2M x 4N), per-wave 128x64 output
//   = 4 m-frags (f=0..3, 32 rows each) x 2 n-frags (g=0..1) x 4 k-steps (32B).
//   LDS 128 KiB double-buffered; T2 XOR swizzle (r1-verified, conflicts=0).
//   Frag layout (32x32x32): lane holds row lane&31, k-chunk (lane>>5)*16B.
//   ds_read addr = rowbase + (lcA ^ k*32), lcA = (lane>>5)*16 ^ ((lane&7)<<4);
//   per quarter-wave: 2 lanes/bank-quad = conflict-free (same as r1).
//   Phase map (frags read ONE PHASE AHEAD, r3; 2 barriers/tile, r4):
//     P0: acc[f01][g] += a(f01,k01)*b(k01) ; read a(f01,k23),b(k23) ;
//         stage ALL 8 of t+1 (B0-3,A0,A2,A1,A3) ; WAITVM(8) ; barrier
//         [WAITVM(8) drains exactly A1,A3(cur) -> gates P1/P2 f23-k01/k23 reads]
//     P1: acc[f01][g] += a(f01,k23)*b(k23) ; read a(f23,k01)
//     P2: acc[f23][g] += a(f23,k01)*b(k01) ; read a(f23,k23) ; WAITVM(2) ; barrier
//         [WAITVM(2) drains B,A0,A2(t+1) -> gates P3's staging-buf reads; barrier
//          is also the WAR fence before t+1's staging overwrites bo]
//     P3: acc[f23][g] += a(f23,k23)*b(k23) ; read a'(f01,k01),b'(k01) from so
//   f01 rows are A0 (wm=0) / A2 (wm=128); f23 rows are A1/A3 -> gating identical
//   to r4. vmcnt never 0 in main loop; peeled last tile drains WAITVM(0).
// ---------------------------------------------------------------------------
__global__ __launch_bounds__(512, 2) void gemm_i8_kernel(const int8_t* __restrict__ A,
                                                         const int8_t* __restrict__ B,
                                                         const float* __restrict__ sx,
                                                         const float* __restrict__ scb,
                                                         float* __restrict__ C) {
  constexpr int BK = 128;
  constexpr int NT = Ktot / BK;  // 32 K-tiles
  __shared__ __align__(16) int8_t lds[131072];

  const int tid = threadIdx.x;
  const int lane = tid & 63;
  const int wid = tid >> 6;

  // T1: XCD-aware swizzle. 512 WGs, 8 XCDs -> each XCD gets 64 consecutive
  // wgids = 4 full m-panel rows (A L2-resident per XCD).
  const int wg = (int)blockIdx.x;
  const int wgs = (wg & 7) * 64 + (wg >> 3);
  const int m0 = (wgs >> 4) * 256;  // 32 m-tiles
  const int n0 = (wgs & 15) * 256;  // 16 n-tiles

  const int wm = (wid >> 2) * 128;  // wave M offset: 0 / 128
  const int wn = (wid & 3) * 64;    // wave N offset: 0/64/128/192

  // Staging: load i covers rows i*64 + tid/8, 16B at column (tid%8)*16,
  // global column inverse-swizzled so the linear LDS write lands swizzled (T2).
  const int srow = tid >> 3;
  const int scol = ((tid & 7) * 16) ^ ((srow & 7) << 4);
  const int8_t* gA = A + (size_t)(m0 + srow) * Ktot + scol;
  const int8_t* gB = B + (size_t)(n0 + srow) * Ktot + scol;

  // Swizzled ds_read column parts for the 32x32x32 fragment layout.
  const int l31 = lane & 31;
  const int lcA = ((lane >> 5) * 16) ^ ((lane & 7) << 4);
  const int kc0 = lcA, kc1 = lcA ^ 32, kc2 = lcA ^ 64, kc3 = lcA ^ 96;
  // Row byte-bases (A half at 0, B half at 65536).
  const int aR0 = (wm + 0 * 32 + l31) * 128;
  const int aR1 = (wm + 1 * 32 + l31) * 128;
  const int aR2 = (wm + 2 * 32 + l31) * 128;
  const int aR3 = (wm + 3 * 32 + l31) * 128;
  const int bR0 = 65536 + (wn + 0 * 32 + l31) * 128;
  const int bR1 = 65536 + (wn + 1 * 32 + l31) * 128;

  i32x16 acc[4][2];
#pragma unroll
  for (int f = 0; f < 4; ++f)
#pragma unroll
    for (int g = 0; g < 2; ++g) acc[f][g] = (i32x16)0;

  // Fragment registers (static indices only, rule 20).
  //   aC[i]/aN[i]: i = fpair*2 + k-within-pair ; bLo = b(k0,k1), bHi = b(k2,k3),
  //   bXx[j]: j = g*2 + k-within-pair. bLo live P3->P2(next); bHi P0->P3.
  i32x4 aC[4], aN[4], bLo[4], bHi[4];

  // Prologue: stage K-tile 0 into buffer 0, order B0-3, A0, A2, A1, A3.
#pragma unroll
  for (int i = 0; i < 4; ++i) GLD16(gB + (size_t)(i * 64) * Ktot, &lds[65536 + i * 8192 + tid * 16]);
  GLD16(gA + (size_t)(0 * 64) * Ktot, &lds[0 * 8192 + tid * 16]);
  GLD16(gA + (size_t)(2 * 64) * Ktot, &lds[2 * 8192 + tid * 16]);
  GLD16(gA + (size_t)(1 * 64) * Ktot, &lds[1 * 8192 + tid * 16]);
  GLD16(gA + (size_t)(3 * 64) * Ktot, &lds[3 * 8192 + tid * 16]);
  WAITVM(2);  // B + A0,A2 landed; A1,A3 in flight (loop-entry invariant = 2)
  __builtin_amdgcn_s_barrier();
  // Pre-read P0 frags of tile 0 (regions B / A0 / A2 of buf0 — all confirmed).
  aC[0] = *(const i32x4*)&lds[aR0 + kc0];
  aC[1] = *(const i32x4*)&lds[aR0 + kc1];
  aC[2] = *(const i32x4*)&lds[aR1 + kc0];
  aC[3] = *(const i32x4*)&lds[aR1 + kc1];
  bLo[0] = *(const i32x4*)&lds[bR0 + kc0];
  bLo[1] = *(const i32x4*)&lds[bR0 + kc1];
  bLo[2] = *(const i32x4*)&lds[bR1 + kc0];
  bLo[3] = *(const i32x4*)&lds[bR1 + kc1];

#pragma unroll 2
  for (int t = 0; t < NT - 1; ++t) {
    const int bo = (t & 1) * 32768;  // compute buffer offset
    const int so = bo ^ 32768;       // staging buffer offset
    const size_t kn = (size_t)(t + 1) * BK;

    // ---- P0: MFMA f01*k01 ; read f01*k23 + b*k23 (cur, valid since end-P2
    //          prev) ; stage ALL of t+1 ; WAITVM(8) ; barrier ----
    aN[0] = *(const i32x4*)&lds[bo + aR0 + kc2];
    aN[1] = *(const i32x4*)&lds[bo + aR0 + kc3];
    aN[2] = *(const i32x4*)&lds[bo + aR1 + kc2];
    aN[3] = *(const i32x4*)&lds[bo + aR1 + kc3];
    bHi[0] = *(const i32x4*)&lds[bo + bR0 + kc2];
    bHi[1] = *(const i32x4*)&lds[bo + bR0 + kc3];
    bHi[2] = *(const i32x4*)&lds[bo + bR1 + kc2];
    bHi[3] = *(const i32x4*)&lds[bo + bR1 + kc3];
#pragma unroll
    for (int i = 0; i < 4; ++i)
      GLD16(gB + kn + (size_t)(i * 64) * Ktot, &lds[65536 + so + i * 8192 + tid * 16]);
    GLD16(gA + kn + (size_t)(0 * 64) * Ktot, &lds[so + 0 * 8192 + tid * 16]);
    GLD16(gA + kn + (size_t)(2 * 64) * Ktot, &lds[so + 2 * 8192 + tid * 16]);
    GLD16(gA + kn + (size_t)(1 * 64) * Ktot, &lds[so + 1 * 8192 + tid * 16]);
    GLD16(gA + kn + (size_t)(3 * 64) * Ktot, &lds[so + 3 * 8192 + tid * 16]);
    __builtin_amdgcn_s_setprio(1);
    acc[0][0] = MFMA32(aC[0], bLo[0], acc[0][0]);
    acc[0][0] = MFMA32(aC[1], bLo[1], acc[0][0]);
    acc[0][1] = MFMA32(aC[0], bLo[2], acc[0][1]);
    acc[0][1] = MFMA32(aC[1], bLo[3], acc[0][1]);
    acc[1][0] = MFMA32(aC[2], bLo[0], acc[1][0]);
    acc[1][0] = MFMA32(aC[3], bLo[1], acc[1][0]);
    acc[1][1] = MFMA32(aC[2], bLo[2], acc[1][1]);
    acc[1][1] = MFMA32(aC[3], bLo[3], acc[1][1]);
    __builtin_amdgcn_s_setprio(0);
    WAITVM(8);
    __builtin_amdgcn_s_barrier();

    // ---- P1: MFMA f01*k23 ; read f23*k01 (A1/A3 — gated by end-P0) ----
    aC[0] = *(const i32x4*)&lds[bo + aR2 + kc0];
    aC[1] = *(const i32x4*)&lds[bo + aR2 + kc1];
    aC[2] = *(const i32x4*)&lds[bo + aR3 + kc0];
    aC[3] = *(const i32x4*)&lds[bo + aR3 + kc1];
    __builtin_amdgcn_s_setprio(1);
    acc[0][0] = MFMA32(aN[0], bHi[0], acc[0][0]);
    acc[0][0] = MFMA32(aN[1], bHi[1], acc[0][0]);
    acc[0][1] = MFMA32(aN[0], bHi[2], acc[0][1]);
    acc[0][1] = MFMA32(aN[1], bHi[3], acc[0][1]);
    acc[1][0] = MFMA32(aN[2], bHi[0], acc[1][0]);
    acc[1][0] = MFMA32(aN[3], bHi[1], acc[1][0]);
    acc[1][1] = MFMA32(aN[2], bHi[2], acc[1][1]);
    acc[1][1] = MFMA32(aN[3], bHi[3], acc[1][1]);
    __builtin_amdgcn_s_setprio(0);

    // ---- P2: MFMA f23*k01 (bLo still live) ; read f23*k23 ;
    //          WAITVM(2) ; barrier (WAR fence for staging into bo) ----
    aN[0] = *(const i32x4*)&lds[bo + aR2 + kc2];
    aN[1] = *(const i32x4*)&lds[bo + aR2 + kc3];
    aN[2] = *(const i32x4*)&lds[bo + aR3 + kc2];
    aN[3] = *(const i32x4*)&lds[bo + aR3 + kc3];
    __builtin_amdgcn_s_setprio(1);
    acc[2][0] = MFMA32(aC[0], bLo[0], acc[2][0]);
    acc[2][0] = MFMA32(aC[1], bLo[1], acc[2][0]);
    acc[2][1] = MFMA32(aC[0], bLo[2], acc[2][1]);
    acc[2][1] = MFMA32(aC[1], bLo[3], acc[2][1]);
    acc[3][0] = MFMA32(aC[2], bLo[0], acc[3][0]);
    acc[3][0] = MFMA32(aC[3], bLo[1], acc[3][0]);
    acc[3][1] = MFMA32(aC[2], bLo[2], acc[3][1]);
    acc[3][1] = MFMA32(aC[3], bLo[3], acc[3][1]);
    __builtin_amdgcn_s_setprio(0);
    WAITVM(2);
    __builtin_amdgcn_s_barrier();

    // ---- P3: MFMA f23*k23 ; read next-tile f01*k01 + b*k01 from `so`
    //          (B/A0/A2 — gated by end-P2) ----
    aC[0] = *(const i32x4*)&lds[so + aR0 + kc0];
    aC[1] = *(const i32x4*)&lds[so + aR0 + kc1];
    aC[2] = *(const i32x4*)&lds[so + aR1 + kc0];
    aC[3] = *(const i32x4*)&lds[so + aR1 + kc1];
    bLo[0] = *(const i32x4*)&lds[so + bR0 + kc0];
    bLo[1] = *(const i32x4*)&lds[so + bR0 + kc1];
    bLo[2] = *(const i32x4*)&lds[so + bR1 + kc0];
    bLo[3] = *(const i32x4*)&lds[so + bR1 + kc1];
    __builtin_amdgcn_s_setprio(1);
    acc[2][0] = MFMA32(aN[0], bHi[0], acc[2][0]);
    acc[2][0] = MFMA32(aN[1], bHi[1], acc[2][0]);
    acc[2][1] = MFMA32(aN[0], bHi[2], acc[2][1]);
    acc[2][1] = MFMA32(aN[1], bHi[3], acc[2][1]);
    acc[3][0] = MFMA32(aN[2], bHi[0], acc[3][0]);
    acc[3][0] = MFMA32(aN[3], bHi[1], acc[3][0]);
    acc[3][1] = MFMA32(aN[2], bHi[2], acc[3][1]);
    acc[3][1] = MFMA32(aN[3], bHi[3], acc[3][1]);
    __builtin_amdgcn_s_setprio(0);
  }

  // ---- Peeled last tile (t = NT-1): no staging; entry outstanding = A1,A3. ----
  {
    const int bo = ((NT - 1) & 1) * 32768;
    // P0: reads of cur A0/A2/B k23 (already gated); MFMA f01*k01; full drain.
    aN[0] = *(const i32x4*)&lds[bo + aR0 + kc2];
    aN[1] = *(const i32x4*)&lds[bo + aR0 + kc3];
    aN[2] = *(const i32x4*)&lds[bo + aR1 + kc2];
    aN[3] = *(const i32x4*)&lds[bo + aR1 + kc3];
    bHi[0] = *(const i32x4*)&lds[bo + bR0 + kc2];
    bHi[1] = *(const i32x4*)&lds[bo + bR0 + kc3];
    bHi[2] = *(const i32x4*)&lds[bo + bR1 + kc2];
    bHi[3] = *(const i32x4*)&lds[bo + bR1 + kc3];
    __builtin_amdgcn_s_setprio(1);
    acc[0][0] = MFMA32(aC[0], bLo[0], acc[0][0]);
    acc[0][0] = MFMA32(aC[1], bLo[1], acc[0][0]);
    acc[0][1] = MFMA32(aC[0], bLo[2], acc[0][1]);
    acc[0][1] = MFMA32(aC[1], bLo[3], acc[0][1]);
    acc[1][0] = MFMA32(aC[2], bLo[0], acc[1][0]);
    acc[1][0] = MFMA32(aC[3], bLo[1], acc[1][0]);
    acc[1][1] = MFMA32(aC[2], bLo[2], acc[1][1]);
    acc[1][1] = MFMA32(aC[3], bLo[3], acc[1][1]);
    __builtin_amdgcn_s_setprio(0);
    WAITVM(0);  // no staging this tile: full drain of A1,A3 before their reads
    __builtin_amdgcn_s_barrier();
    // P1: MFMA f01*k23 ; read f23*k01
    aC[0] = *(const i32x4*)&lds[bo + aR2 + kc0];
    aC[1] = *(const i32x4*)&lds[bo + aR2 + kc1];
    aC[2] = *(const i32x4*)&lds[bo + aR3 + kc0];
    aC[3] = *(const i32x4*)&lds[bo + aR3 + kc1];
    __builtin_amdgcn_s_setprio(1);
    acc[0][0] = MFMA32(aN[0], bHi[0], acc[0][0]);
    acc[0][0] = MFMA32(aN[1], bHi[1], acc[0][0]);
    acc[0][1] = MFMA32(aN[0], bHi[2], acc[0][1]);
    acc[0][1] = MFMA32(aN[1], bHi[3], acc[0][1]);
    acc[1][0] = MFMA32(aN[2], bHi[0], acc[1][0]);
    acc[1][0] = MFMA32(aN[3], bHi[1], acc[1][0]);
    acc[1][1] = MFMA32(aN[2], bHi[2], acc[1][1]);
    acc[1][1] = MFMA32(aN[3], bHi[3], acc[1][1]);
    __builtin_amdgcn_s_setprio(0);
    // P2: MFMA f23*k01 ; read f23*k23
    aN[0] = *(const i32x4*)&lds[bo + aR2 + kc2];
    aN[1] = *(const i32x4*)&lds[bo + aR2 + kc3];
    aN[2] = *(const i32x4*)&lds[bo + aR3 + kc2];
    aN[3] = *(const i32x4*)&lds[bo + aR3 + kc3];
    __builtin_amdgcn_s_setprio(1);
    acc[2][0] = MFMA32(aC[0], bLo[0], acc[2][0]);
    acc[2][0] = MFMA32(aC[1], bLo[1], acc[2][0]);
    acc[2][1] = MFMA32(aC[0], bLo[2], acc[2][1]);
    acc[2][1] = MFMA32(aC[1], bLo[3], acc[2][1]);
    acc[3][0] = MFMA32(aC[2], bLo[0], acc[3][0]);
    acc[3][0] = MFMA32(aC[3], bLo[1], acc[3][0]);
    acc[3][1] = MFMA32(aC[2], bLo[2], acc[3][1]);
    acc[3][1] = MFMA32(aC[3], bLo[3], acc[3][1]);
    __builtin_amdgcn_s_setprio(0);
    // P3: MFMA f23*k23
    __builtin_amdgcn_s_setprio(1);
    acc[2][0] = MFMA32(aN[0], bHi[0], acc[2][0]);
    acc[2][0] = MFMA32(aN[1], bHi[1], acc[2][0]);
    acc[2][1] = MFMA32(aN[0], bHi[2], acc[2][1]);
    acc[2][1] = MFMA32(aN[1], bHi[3], acc[2][1]);
    acc[3][0] = MFMA32(aN[2], bHi[0], acc[3][0]);
    acc[3][0] = MFMA32(aN[3], bHi[1], acc[3][0]);
    acc[3][1] = MFMA32(aN[2], bHi[2], acc[3][1]);
    acc[3][1] = MFMA32(aN[3], bHi[3], acc[3][1]);
    __builtin_amdgcn_s_setprio(0);
  }

  // Epilogue: 32x32 C/D layout (HW-verified m74/m101, dtype-independent):
  // col = lane&31, row = (reg&3) + 8*(reg>>2) + 4*(lane>>5), reg in [0,16).
  // y = acc * sx[m] * (SCB[n]/127).
  const int col = l31;
  const int hi4 = (lane >> 5) * 4;
#pragma unroll
  for (int f = 0; f < 4; ++f) {
    const int gmb = m0 + wm + f * 32;
    float sm[16];
#pragma unroll
    for (int q = 0; q < 4; ++q)
#pragma unroll
      for (int r = 0; r < 4; ++r) sm[q * 4 + r] = sx[gmb + r + 8 * q + hi4];
#pragma unroll
    for (int g = 0; g < 2; ++g) {
      const int gn = n0 + wn + g * 32 + col;
      const float snv = scb[gn] * (1.0f / 127.0f);
#pragma unroll
      for (int q = 0; q < 4; ++q)
#pragma unroll
        for (int r = 0; r < 4; ++r) {
          const int row = r + 8 * q + hi4;
          C[(size_t)(gmb + row) * Ntot + gn] = (float)acc[f][g][q * 4 + r] * sm[q * 4 + r] * snv;
        }
    }
  }
}

// ---------------------------------------------------------------------------
extern "C" void kernel_launch(void* const* d_in, const int* in_sizes, int n_in,
                              void* d_out, int out_size, void* d_ws, size_t ws_size,
                              hipStream_t stream) {
  const float* x = (const float*)d_in[0];
  const int* CB32 = (const int*)d_in[1];  // harness: integer inputs -> const int*
  const float* SCB = (const float*)d_in[2];
  float* out = (float*)d_out;

  // ws layout: xq (32 MB) | cb8 (16 MB) | sx (32 KB)  => needs ~48.03 MB
  int8_t* xq = (int8_t*)d_ws;
  int8_t* cb8 = (int8_t*)d_ws + (size_t)Mtot * Ktot;
  float* sx = (float*)((int8_t*)d_ws + (size_t)Mtot * Ktot + (size_t)Ntot * Ktot);

  // fused prep: 16384 pack blocks + 8192 quant blocks
  prep_kernel<<<16384 + Mtot, 256, 0, stream>>>(CB32, cb8, x, xq, sx);
  // 256x256 tiles: (8192/256) * (4096/256) = 32*16 = 512 WGs (flattened, XCD-swizzled)
  gemm_i8_kernel<<<512, 512, 0, stream>>>(xq, cb8, sx, SCB, out);
}

// Round 6
// 378.447 us; speedup vs baseline: 1.0200x; 1.0200x over previous
//
#include <hip/hip_runtime.h>
#include <stdint.h>

// Problem shape (fixed by reference): x[4,2048,4096] f32, CB[4096,4096] i8, SCB[4096] f32
static constexpr int Mtot = 8192;   // B*S
static constexpr int Ntot = 4096;   // OUT
static constexpr int Ktot = 4096;   // IN

using i32x4 = __attribute__((ext_vector_type(4))) int;

#define GLD16(gptr, lptr)                                                                   \
  __builtin_amdgcn_global_load_lds((const __attribute__((address_space(1))) void*)(gptr),   \
                                   (__attribute__((address_space(3))) void*)(lptr), 16, 0, 0)
#define WAITVM(N) asm volatile("s_waitcnt vmcnt(" #N ")" ::: "memory")
#define MFMA16(a, b, c) __builtin_amdgcn_mfma_i32_16x16x64_i8((a), (b), (c), 0, 0, 0)

// ---------------------------------------------------------------------------
// Kernel 1 (fused prep):
//  blocks [0, 16384)      : repack CB int32 -> int8
//  blocks [16384, 24576)  : row-wise dynamic int8 quant of x (one block/row)
// ---------------------------------------------------------------------------
__global__ __launch_bounds__(256) void prep_kernel(const int* __restrict__ cb32,
                                                   int8_t* __restrict__ cb8,
                                                   const float* __restrict__ x,
                                                   int8_t* __restrict__ xq,
                                                   float* __restrict__ sx) {
  __shared__ float wmax[4];
  if (blockIdx.x < 16384) {
    const int idx = blockIdx.x * 256 + threadIdx.x;  // one int4 -> one packed int
    const int4 v = reinterpret_cast<const int4*>(cb32)[idx];
    const unsigned packed = (unsigned)(v.x & 0xff) | ((unsigned)(v.y & 0xff) << 8) |
                            ((unsigned)(v.z & 0xff) << 16) | ((unsigned)(v.w & 0xff) << 24);
    reinterpret_cast<unsigned*>(cb8)[idx] = packed;
    return;
  }
  const int row = blockIdx.x - 16384;
  const float4* xr = reinterpret_cast<const float4*>(x + (size_t)row * Ktot);
  float4 v[4];
  float am = 0.f;
#pragma unroll
  for (int i = 0; i < 4; ++i) {
    v[i] = xr[threadIdx.x + i * 256];
    am = fmaxf(am, fmaxf(fmaxf(fabsf(v[i].x), fabsf(v[i].y)),
                         fmaxf(fabsf(v[i].z), fabsf(v[i].w))));
  }
#pragma unroll
  for (int off = 32; off > 0; off >>= 1) am = fmaxf(am, __shfl_xor(am, off));
  if ((threadIdx.x & 63) == 0) wmax[threadIdx.x >> 6] = am;
  __syncthreads();
  am = fmaxf(fmaxf(wmax[0], wmax[1]), fmaxf(wmax[2], wmax[3]));
  const float inv = 127.0f / am;
  if (threadIdx.x == 0) sx[row] = am * (1.0f / 127.0f);
  unsigned* dq = reinterpret_cast<unsigned*>(xq + (size_t)row * Ktot);
#pragma unroll
  for (int i = 0; i < 4; ++i) {
    const int q0 = (int)rintf(v[i].x * inv);
    const int q1 = (int)rintf(v[i].y * inv);
    const int q2 = (int)rintf(v[i].z * inv);
    const int q3 = (int)rintf(v[i].w * inv);
    dq[threadIdx.x + i * 256] = (unsigned)(q0 & 0xff) | ((unsigned)(q1 & 0xff) << 8) |
                                ((unsigned)(q2 & 0xff) << 16) | ((unsigned)(q3 & 0xff) << 24);
  }
}

// ---------------------------------------------------------------------------
// Kernel 2: int8 GEMM, 256x256 tile. r6: 16 waves (1024 thr, 4M x 4N),
// per-wave 64x64 -> acc = 64 AGPR -> 4 waves/SIMD (TLP). Back to 16x16x64
// MFMA (r5's 32x32 has an inherent 4-way LDS conflict: 32-row frag reads >
// 8-chunk swizzle space). __launch_bounds__(1024,4) forces total regs <=128.
//   BK=128, LDS 128 KiB dbuf: A [0,64K) (32K/buf), B [64K,128K).
//   T2 swizzle unchanged (16-row frag reads, conflict-free, r1-verified).
//   Staging: 4 GLD16/tile (1024thr x 16B = 16KB each), order A0,A1,B0,B1 @P0.
//   Gates: end-P2 WAITVM(2) drains A(t+1) -> P3 pre-reads a(t+1,h0);
//          end-P3 WAITVM(0) drains B(t+1) (3-phase cover ~2000cyc >> HBM 900)
//          + barrier (also WAR fence) -> read b(t+1,h0,g01) at loop bottom.
//   2 barriers/tile; all tile-t regions gated at tile entry; waves drift
//   freely across P0->P2 (TLP absorbs per-wave lgkm exposure).
//   Phase map (per wave, 32 MFMA/tile; h = k-half, g = n-frag):
//     P0: acc[f][0,1] += a(h0)*b(h0,g01) ; read b(h0,g23)      ; stage t+1
//     P1: acc[f][2,3] += a(h0)*b(h0,g23) ; read b(h1,g01)
//     P2: acc[f][0,1] += a(h1)*b(h1,g01) ; read a(h1)@top, b(h1,g23) ; VM2 ; bar
//     P3: acc[f][2,3] += a(h1)*b(h1,g23) ; read a'(h0) from so ; VM0 ; bar ;
//         read b'(h0,g01) from so
// ---------------------------------------------------------------------------
__global__ __launch_bounds__(1024, 4) void gemm_i8_kernel(const int8_t* __restrict__ A,
                                                          const int8_t* __restrict__ B,
                                                          const float* __restrict__ sx,
                                                          const float* __restrict__ scb,
                                                          float* __restrict__ C) {
  constexpr int BK = 128;
  constexpr int NT = Ktot / BK;  // 32 K-tiles
  constexpr size_t ROWS128 = (size_t)128 * Ktot;
  __shared__ __align__(16) int8_t lds[131072];

  const int tid = threadIdx.x;  // 0..1023
  const int lane = tid & 63;
  const int wid = tid >> 6;  // 0..15

  // T1: XCD-aware swizzle. 512 WGs, 8 XCDs -> each XCD gets 64 consecutive
  // wgids = 4 full m-panel rows (A L2-resident per XCD).
  const int wg = (int)blockIdx.x;
  const int wgs = (wg & 7) * 64 + (wg >> 3);
  const int m0 = (wgs >> 4) * 256;  // 32 m-tiles
  const int n0 = (wgs & 15) * 256;  // 16 n-tiles

  const int wm = (wid >> 2) * 64;  // wave M offset: 0/64/128/192
  const int wn = (wid & 3) * 64;   // wave N offset: 0/64/128/192

  // Staging: row = tid/8 (0..127), 16B at column (tid%8)*16, global column
  // inverse-swizzled so the linear LDS write lands T2-swizzled.
  const int srow = tid >> 3;
  const int scol = ((tid & 7) * 16) ^ ((srow & 7) << 4);
  const int8_t* gA = A + (size_t)(m0 + srow) * Ktot + scol;
  const int8_t* gB = B + (size_t)(n0 + srow) * Ktot + scol;

  // Swizzled ds_read offsets (identical math to r4; row&7 == lane&7).
  const int l15 = lane & 15;
  const int lc0 = ((lane >> 4) * 16) ^ ((lane & 7) << 4);
  const int aOff = (wm + l15) * 128 + lc0;          // + f*2048 ; ^64 for h1
  const int bOff = 65536 + (wn + l15) * 128 + lc0;  // + g*2048 ; ^64 for h1

  i32x4 acc[4][4];
#pragma unroll
  for (int f = 0; f < 4; ++f)
#pragma unroll
    for (int g = 0; g < 4; ++g) acc[f][g] = (i32x4)0;

  // Fragment registers (static indices only, rule 20).
  i32x4 aH[4], aN[4], bA[2], bB[2], bC[2], bD[2];

  // Prologue: stage K-tile 0 into buffer 0 (A0,A1,B0,B1); full drain; pre-read.
  GLD16(gA, &lds[tid * 16]);
  GLD16(gA + ROWS128, &lds[16384 + tid * 16]);
  GLD16(gB, &lds[65536 + tid * 16]);
  GLD16(gB + ROWS128, &lds[65536 + 16384 + tid * 16]);
  WAITVM(0);
  __builtin_amdgcn_s_barrier();
#pragma unroll
  for (int f = 0; f < 4; ++f) aH[f] = *(const i32x4*)&lds[aOff + f * 2048];
  bA[0] = *(const i32x4*)&lds[bOff];
  bA[1] = *(const i32x4*)&lds[bOff + 2048];

  for (int t = 0; t < NT - 1; ++t) {
    const int bo = (t & 1) * 32768;  // compute buffer offset
    const int so = bo ^ 32768;       // staging buffer offset
    const size_t kn = (size_t)(t + 1) * BK;

    // ---- P0: MFMA a(h0)*b(h0,g01) ; read b(h0,g23) ; stage ALL of t+1 ----
    bB[0] = *(const i32x4*)&lds[bo + bOff + 2 * 2048];
    bB[1] = *(const i32x4*)&lds[bo + bOff + 3 * 2048];
    GLD16(gA + kn, &lds[so + tid * 16]);
    GLD16(gA + ROWS128 + kn, &lds[so + 16384 + tid * 16]);
    GLD16(gB + kn, &lds[65536 + so + tid * 16]);
    GLD16(gB + ROWS128 + kn, &lds[65536 + so + 16384 + tid * 16]);
    __builtin_amdgcn_s_setprio(1);
#pragma unroll
    for (int f = 0; f < 4; ++f) {
      acc[f][0] = MFMA16(aH[f], bA[0], acc[f][0]);
      acc[f][1] = MFMA16(aH[f], bA[1], acc[f][1]);
    }
    __builtin_amdgcn_s_setprio(0);

    // ---- P1: MFMA a(h0)*b(h0,g23) ; read b(h1,g01) ----
    bC[0] = *(const i32x4*)&lds[bo + (bOff ^ 64)];
    bC[1] = *(const i32x4*)&lds[bo + (bOff ^ 64) + 2048];
    __builtin_amdgcn_s_setprio(1);
#pragma unroll
    for (int f = 0; f < 4; ++f) {
      acc[f][2] = MFMA16(aH[f], bB[0], acc[f][2]);
      acc[f][3] = MFMA16(aH[f], bB[1], acc[f][3]);
    }
    __builtin_amdgcn_s_setprio(0);

    // ---- P2: read a(h1) (zero-ahead, TLP absorbs) + b(h1,g23) ;
    //          MFMA a(h1)*b(h1,g01) ; WAITVM(2) [drains A(t+1)] ; barrier ----
#pragma unroll
    for (int f = 0; f < 4; ++f) aN[f] = *(const i32x4*)&lds[bo + (aOff ^ 64) + f * 2048];
    bD[0] = *(const i32x4*)&lds[bo + (bOff ^ 64) + 2 * 2048];
    bD[1] = *(const i32x4*)&lds[bo + (bOff ^ 64) + 3 * 2048];
    __builtin_amdgcn_s_setprio(1);
#pragma unroll
    for (int f = 0; f < 4; ++f) {
      acc[f][0] = MFMA16(aN[f], bC[0], acc[f][0]);
      acc[f][1] = MFMA16(aN[f], bC[1], acc[f][1]);
    }
    __builtin_amdgcn_s_setprio(0);
    WAITVM(2);
    __builtin_amdgcn_s_barrier();

    // ---- P3: read a'(t+1,h0) from so [gated by end-P2] ; MFMA a(h1)*b(h1,g23)
    //          WAITVM(0) [drains B(t+1), 3-phase cover] ; barrier [WAR fence] ;
    //          read b'(t+1,h0,g01) from so ----
#pragma unroll
    for (int f = 0; f < 4; ++f) aH[f] = *(const i32x4*)&lds[so + aOff + f * 2048];
    __builtin_amdgcn_s_setprio(1);
#pragma unroll
    for (int f = 0; f < 4; ++f) {
      acc[f][2] = MFMA16(aN[f], bD[0], acc[f][2]);
      acc[f][3] = MFMA16(aN[f], bD[1], acc[f][3]);
    }
    __builtin_amdgcn_s_setprio(0);
    WAITVM(0);
    __builtin_amdgcn_s_barrier();
    bA[0] = *(const i32x4*)&lds[so + bOff];
    bA[1] = *(const i32x4*)&lds[so + bOff + 2048];
  }

  // ---- Peeled last tile (t = NT-1): everything staged & drained; no sync ----
  {
    const int bo = ((NT - 1) & 1) * 32768;
    bB[0] = *(const i32x4*)&lds[bo + bOff + 2 * 2048];
    bB[1] = *(const i32x4*)&lds[bo + bOff + 3 * 2048];
    __builtin_amdgcn_s_setprio(1);
#pragma unroll
    for (int f = 0; f < 4; ++f) {
      acc[f][0] = MFMA16(aH[f], bA[0], acc[f][0]);
      acc[f][1] = MFMA16(aH[f], bA[1], acc[f][1]);
    }
    __builtin_amdgcn_s_setprio(0);
    bC[0] = *(const i32x4*)&lds[bo + (bOff ^ 64)];
    bC[1] = *(const i32x4*)&lds[bo + (bOff ^ 64) + 2048];
    __builtin_amdgcn_s_setprio(1);
#pragma unroll
    for (int f = 0; f < 4; ++f) {
      acc[f][2] = MFMA16(aH[f], bB[0], acc[f][2]);
      acc[f][3] = MFMA16(aH[f], bB[1], acc[f][3]);
    }
    __builtin_amdgcn_s_setprio(0);
#pragma unroll
    for (int f = 0; f < 4; ++f) aN[f] = *(const i32x4*)&lds[bo + (aOff ^ 64) + f * 2048];
    bD[0] = *(const i32x4*)&lds[bo + (bOff ^ 64) + 2 * 2048];
    bD[1] = *(const i32x4*)&lds[bo + (bOff ^ 64) + 3 * 2048];
    __builtin_amdgcn_s_setprio(1);
#pragma unroll
    for (int f = 0; f < 4; ++f) {
      acc[f][0] = MFMA16(aN[f], bC[0], acc[f][0]);
      acc[f][1] = MFMA16(aN[f], bC[1], acc[f][1]);
      acc[f][2] = MFMA16(aN[f], bD[0], acc[f][2]);
      acc[f][3] = MFMA16(aN[f], bD[1], acc[f][3]);
    }
    __builtin_amdgcn_s_setprio(0);
  }

  // Epilogue: C/D layout col=lane&15, row=(lane>>4)*4+reg (HW-verified,
  // dtype-independent). y = acc * sx[m] * (SCB[n]/127).
  const int col = lane & 15;
  const int rbase = (lane >> 4) * 4;
#pragma unroll
  for (int f = 0; f < 4; ++f) {
    const int gmb = m0 + wm + f * 16 + rbase;
    float sm[4];
#pragma unroll
    for (int r = 0; r < 4; ++r) sm[r] = sx[gmb + r];
#pragma unroll
    for (int g = 0; g < 4; ++g) {
      const int gn = n0 + wn + g * 16 + col;
      const float snv = scb[gn] * (1.0f / 127.0f);
#pragma unroll
      for (int r = 0; r < 4; ++r)
        C[(size_t)(gmb + r) * Ntot + gn] = (float)acc[f][g][r] * sm[r] * snv;
    }
  }
}

// ---------------------------------------------------------------------------
extern "C" void kernel_launch(void* const* d_in, const int* in_sizes, int n_in,
                              void* d_out, int out_size, void* d_ws, size_t ws_size,
                              hipStream_t stream) {
  const float* x = (const float*)d_in[0];
  const int* CB32 = (const int*)d_in[1];  // harness: integer inputs -> const int*
  const float* SCB = (const float*)d_in[2];
  float* out = (float*)d_out;

  // ws layout: xq (32 MB) | cb8 (16 MB) | sx (32 KB)  => needs ~48.03 MB
  int8_t* xq = (int8_t*)d_ws;
  int8_t* cb8 = (int8_t*)d_ws + (size_t)Mtot * Ktot;
  float* sx = (float*)((int8_t*)d_ws + (size_t)Mtot * Ktot + (size_t)Ntot * Ktot);

  // fused prep: 16384 pack blocks + 8192 quant blocks
  prep_kernel<<<16384 + Mtot, 256, 0, stream>>>(CB32, cb8, x, xq, sx);
  // 256x256 tiles: (8192/256) * (4096/256) = 32*16 = 512 WGs (flattened,
  // XCD-swizzled), 1024 threads = 16 waves (4 waves/SIMD).
  gemm_i8_kernel<<<512, 1024, 0, stream>>>(xq, cb8, sx, SCB, out);
}